// Round 5
// baseline (2333.928 us; speedup 1.0000x reference)
//
#include <hip/hip_runtime.h>
#include <hip/hip_bf16.h>

// Seq2Seq (batch=1): enc LSTM (S=256) -> dec LSTM (T=256, teacher forcing)
// -> linear (VOUT=32000) -> log_softmax.
//
// v6: v5's two-phase poll added a serial LLC round trip (1458->1567us) --
// reverted to v4's combined detect+data poll (all threads, own 4 words).
// New producer chain: thread (jl,ks) computes the 4 GATES of one hidden j;
// half-wave shfl-reduce lands all 4 gate sums in lane 0/32, which finalizes
// and publishes IN PLACE -- no sg LDS hop, no pre-finalize barrier, finalize
// parallel across 4 waves. xg loads hoisted before the poll (hide under
// handoff wait). One loop-end barrier remains as the sh WAR guard.

#define HDIM 1024
#define SLEN 256
#define TLEN 256
#define VOUTN 32000
#define G4 4096
#define NWGC 128      // workgroups in persistent kernel (co-resident on 256 CUs)
#define HPW 8         // hidden indices per WG = 1024/128

typedef __bf16 bf16_t;
typedef __bf16 bf16x8 __attribute__((ext_vector_type(8)));
typedef float f32x4 __attribute__((ext_vector_type(4)));
typedef unsigned long long u64;

static __device__ inline bf16x8 cvt8(float4 a, float4 b) {
    bf16x8 r;
    r[0] = (__bf16)a.x; r[1] = (__bf16)a.y; r[2] = (__bf16)a.z; r[3] = (__bf16)a.w;
    r[4] = (__bf16)b.x; r[5] = (__bf16)b.y; r[6] = (__bf16)b.z; r[7] = (__bf16)b.w;
    return r;
}

static __device__ inline float sig_f(float x) {
    return 1.f / (1.f + __expf(-x));
}
static __device__ inline float tanh_f(float x) {
    float e = __expf(-2.f * fabsf(x));        // in (0,1], no overflow
    float r = (1.f - e) / (1.f + e);
    return copysignf(r, x);
}

// enc+dec input GEMM: out[t][n] = dot(emb[tok(t)], W[n]) + bih[n] + bhh[n]
// 512 blocks x 64 thr; blocks 0..255 encoder, 256..511 decoder.
// Also zeroes hseq (tag 0 invalid) -> no hipMemsetAsync needed.
__global__ __launch_bounds__(64) void xw_all(
    const int* __restrict__ src, const int* __restrict__ trg,
    const int* __restrict__ start,
    const float* __restrict__ enc_emb, const float* __restrict__ enc_Wih,
    const float* __restrict__ enc_bih, const float* __restrict__ enc_bhh,
    const float* __restrict__ dec_emb, const float* __restrict__ dec_Wih,
    const float* __restrict__ dec_bih, const float* __restrict__ dec_bhh,
    float* __restrict__ encXW, float* __restrict__ decXW,
    u64* __restrict__ hseq)          // [512,1024] -> zeroed here
{
    const int b = blockIdx.x, tid = threadIdx.x;

    for (size_t i = (size_t)b * 64 + tid; i < (size_t)512 * 1024; i += (size_t)512 * 64)
        hseq[i] = 0ULL;

    const bool enc = (b < 256);
    const int*   toks = enc ? src : trg;
    const float* emb  = enc ? enc_emb : dec_emb;
    const float* W    = enc ? enc_Wih : dec_Wih;
    const float* bi   = enc ? enc_bih : dec_bih;
    const float* bh   = enc ? enc_bhh : dec_bhh;
    float*       outp = enc ? encXW : decXW;

    __shared__ int stok[SLEN];
    for (int i = tid; i < SLEN; i += 64)
        stok[i] = enc ? toks[i] : (i == 0 ? start[0] : toks[i - 1]);
    __syncthreads();

    const int l15 = tid & 15, quad = tid >> 4;
    const int n = (b & 255) * 16 + l15;
    const float* wrow = W + (size_t)n * HDIM + quad * 8;

    f32x4 acc[16] = {};
    for (int kt = 0; kt < HDIM / 32; ++kt) {
        float4 b0 = *(const float4*)(wrow + kt * 32);
        float4 b1 = *(const float4*)(wrow + kt * 32 + 4);
        bf16x8 bf = cvt8(b0, b1);
#pragma unroll
        for (int mt = 0; mt < 16; ++mt) {
            const float* ar = emb + (size_t)stok[mt * 16 + l15] * HDIM + kt * 32 + quad * 8;
            bf16x8 af = cvt8(*(const float4*)ar, *(const float4*)(ar + 4));
            acc[mt] = __builtin_amdgcn_mfma_f32_16x16x32_bf16(af, bf, acc[mt], 0, 0, 0);
        }
    }
    float bias = bi[n] + bh[n];
#pragma unroll
    for (int mt = 0; mt < 16; ++mt)
#pragma unroll
        for (int r = 0; r < 4; ++r) {
            int t = mt * 16 + quad * 4 + r;
            outp[(size_t)t * G4 + n] = acc[mt][r] + bias;
        }
}

// Persistent recurrence: 512 LSTM steps, tagged-h dataflow sync.
// 128 WGs x 256 thr. WG b owns hidden j in [b*8, b*8+8).
// Thread (jl = tid>>5, ks = tid&31) holds the 4 GATE rows of hidden j0+jl
// over k in [ks*32, ks*32+32) -- w[4][8] float4 = 128 VGPRs, resident.
// Half-wave shfl-reduce over ks lands all 4 gate sums in lane ks==0, which
// finalizes + publishes in place (8 finalize lanes spread over 4 waves).
// h for step t lives in hseq[t][j] as ((u64)t<<32)|f32bits (agent atomics;
// fresh buffer per step; tag 0 invalid).
__global__ __launch_bounds__(256, 1) void lstm_seq(
    const float* __restrict__ encXW,  // [256, 4096]
    const float* __restrict__ decXW,  // [256, 4096]
    const float* __restrict__ encWhh, // [4096, 1024]
    const float* __restrict__ decWhh, // [4096, 1024]
    u64* __restrict__ hseq,           // [512, 1024] tagged h (zeroed by xw_all)
    bf16_t* __restrict__ Hs)          // [256, 1024] decoder h history (bf16)
{
    // padded h stage: word q stored at q + (q>>5) -> half-wave stride-32
    // b32 reads are bank-conflict-free
    __shared__ float sh[HDIM + HDIM / 32];

    const int tid = threadIdx.x;
    const int wg = blockIdx.x;
    const int jl = tid >> 5;                   // local hidden 0..7 (half-wave)
    const int ks = tid & 31;                   // k-chunk index within half-wave
    const int j0 = wg * HPW;
    const bool fin = (ks == 0);
    const int jfin = j0 + jl;

    float4 w[4][8];  // Whh rows {g*1024 + j0+jl}, k in [ks*32, ks*32+32)
    auto load_w = [&](const float* __restrict__ Wsrc) {
#pragma unroll
        for (int g = 0; g < 4; ++g) {
            const float* srcp = Wsrc + (size_t)(g * HDIM + j0 + jl) * HDIM + ks * 32;
#pragma unroll
            for (int i = 0; i < 8; ++i) w[g][i] = *(const float4*)(srcp + i * 4);
        }
    };
    load_w(encWhh);

    float creg = 0.f;  // finalize lanes: c[jfin], persistent across steps

    for (int t = 0; t < SLEN + TLEN; ++t) {
        if (t == SLEN) load_w(decWhh);  // enc -> dec weight swap (one-time)

        // xg prefetch for finalize lanes, issued BEFORE the poll: its ~300cy
        // L2 latency hides entirely under the h handoff wait.
        float xg0 = 0.f, xg1 = 0.f, xg2 = 0.f, xg3 = 0.f;
        if (fin) {
            const float* xw = (t < SLEN) ? encXW + (size_t)t * G4
                                         : decXW + (size_t)(t - SLEN) * G4;
            xg0 = xw[0 * HDIM + jfin];
            xg1 = xw[1 * HDIM + jfin];
            xg2 = xw[2 * HDIM + jfin];
            xg3 = xw[3 * HDIM + jfin];
        }

        // ---- stage h into LDS: combined detect+data poll (v4 style) ----
        // thread owns words q = tid*4 .. tid*4+3 (32 B, 1-2 lines)
        const int q = tid << 2;
        const int pad = q >> 5;               // constant over the 4 words
        if (t == 0) {
            sh[q + pad]     = 0.f;
            sh[q + pad + 1] = 0.f;
            sh[q + pad + 2] = 0.f;
            sh[q + pad + 3] = 0.f;
        } else {
            const u64* hin = hseq + (size_t)t * HDIM + q;
            const unsigned tag = (unsigned)t;
            u64 v0, v1, v2, v3;
            for (;;) {
                v0 = __hip_atomic_load(hin + 0, __ATOMIC_RELAXED, __HIP_MEMORY_SCOPE_AGENT);
                v1 = __hip_atomic_load(hin + 1, __ATOMIC_RELAXED, __HIP_MEMORY_SCOPE_AGENT);
                v2 = __hip_atomic_load(hin + 2, __ATOMIC_RELAXED, __HIP_MEMORY_SCOPE_AGENT);
                v3 = __hip_atomic_load(hin + 3, __ATOMIC_RELAXED, __HIP_MEMORY_SCOPE_AGENT);
                if ((unsigned)(v0 >> 32) == tag && (unsigned)(v1 >> 32) == tag &&
                    (unsigned)(v2 >> 32) == tag && (unsigned)(v3 >> 32) == tag) break;
                __builtin_amdgcn_s_sleep(1);
            }
            sh[q + pad]     = __uint_as_float((unsigned)v0);
            sh[q + pad + 1] = __uint_as_float((unsigned)v1);
            sh[q + pad + 2] = __uint_as_float((unsigned)v2);
            sh[q + pad + 3] = __uint_as_float((unsigned)v3);
        }
        __syncthreads();

        // h chunk -> registers (conflict-free b32 reads, broadcast across jl)
        float hv[32];
#pragma unroll
        for (int i = 0; i < 32; ++i) hv[i] = sh[ks * 33 + i];

        // 4 gate rows x 32 MACs from registers
        float s0 = 0.f, s1 = 0.f, s2 = 0.f, s3 = 0.f;
#pragma unroll
        for (int i = 0; i < 8; ++i) {
            float hx = hv[4 * i], hy = hv[4 * i + 1], hz = hv[4 * i + 2], hw = hv[4 * i + 3];
            s0 += w[0][i].x * hx + w[0][i].y * hy + w[0][i].z * hz + w[0][i].w * hw;
            s1 += w[1][i].x * hx + w[1][i].y * hy + w[1][i].z * hz + w[1][i].w * hw;
            s2 += w[2][i].x * hx + w[2][i].y * hy + w[2][i].z * hz + w[2][i].w * hw;
            s3 += w[3][i].x * hx + w[3][i].y * hy + w[3][i].z * hz + w[3][i].w * hw;
        }
        // reduce over the 32 ks-lanes (half-wave): lane ks==0 gets all 4 gates
#pragma unroll
        for (int o = 16; o; o >>= 1) {
            s0 += __shfl_down(s0, o, 32);
            s1 += __shfl_down(s1, o, 32);
            s2 += __shfl_down(s2, o, 32);
            s3 += __shfl_down(s3, o, 32);
        }

        // finalize + publish IN PLACE (8 lanes, parallel across 4 waves)
        if (fin) {
            float gi = s0 + xg0;
            float gf = s1 + xg1;
            float gg = s2 + xg2;
            float go = s3 + xg3;
            float ii = sig_f(gi);
            float ff = sig_f(gf);
            float g  = tanh_f(gg);
            float oo = sig_f(go);
            float cn = ff * creg + ii * g;
            float hn = oo * tanh_f(cn);
            creg = cn;
            if (t >= SLEN) Hs[(size_t)(t - SLEN) * HDIM + jfin] = (bf16_t)hn;
            if (t < SLEN + TLEN - 1) {
                u64 pk = ((u64)(unsigned)(t + 1) << 32) | (u64)__float_as_uint(hn);
                __hip_atomic_store(hseq + (size_t)(t + 1) * HDIM + jfin, pk,
                                   __ATOMIC_RELAXED, __HIP_MEMORY_SCOPE_AGENT);
            }
        }
        // WAR guard: a thread's next-step poll success does NOT order it
        // against its OWN WG's slower waves still reading sh (its polled
        // words come from a different producer WG). Barrier required.
        __syncthreads();
    }
}

// logits[t][n] = dot(Hs_bf16[t], lin_W[n]) + b[n]
__global__ __launch_bounds__(256) void out_gemm(
    const bf16_t* __restrict__ Hs,   // [256, 1024] bf16
    const float* __restrict__ W,     // [32000, 1024]
    const float* __restrict__ bias,  // [32000]
    float* __restrict__ out)         // [256, 32000]
{
    int tid = threadIdx.x;
    int wave = tid >> 6, lane = tid & 63;
    int l15 = lane & 15, quad = lane >> 4;
    int n = (blockIdx.x * 4 + wave) * 16 + l15;
    const float* wrow = W + (size_t)n * HDIM + quad * 8;

    f32x4 acc[16] = {};
    for (int kt = 0; kt < HDIM / 32; ++kt) {
        float4 b0 = *(const float4*)(wrow + kt * 32);
        float4 b1 = *(const float4*)(wrow + kt * 32 + 4);
        bf16x8 bf = cvt8(b0, b1);
#pragma unroll
        for (int mt = 0; mt < 16; ++mt) {
            bf16x8 af = *(const bf16x8*)(Hs + (size_t)(mt * 16 + l15) * HDIM + kt * 32 + quad * 8);
            acc[mt] = __builtin_amdgcn_mfma_f32_16x16x32_bf16(af, bf, acc[mt], 0, 0, 0);
        }
    }
    float bv = bias[n];
#pragma unroll
    for (int mt = 0; mt < 16; ++mt)
#pragma unroll
        for (int r = 0; r < 4; ++r) {
            int t = mt * 16 + quad * 4 + r;
            out[(size_t)t * VOUTN + n] = acc[mt][r] + bv;
        }
}

// in-place log_softmax per row; 256 blocks (one per t) x 1024 thr, float4
__global__ __launch_bounds__(1024) void log_softmax_k(float* __restrict__ out)
{
    float* row = out + (size_t)blockIdx.x * VOUTN;
    float4* r4 = (float4*)row;
    const int tid = threadIdx.x;
    const int wave = tid >> 6, lane = tid & 63;
    __shared__ float sred[16];

    float m = -1e30f;
    for (int i = tid; i < VOUTN / 4; i += 1024) {
        float4 v = r4[i];
        m = fmaxf(fmaxf(fmaxf(m, v.x), fmaxf(v.y, v.z)), v.w);
    }
    for (int o = 32; o; o >>= 1) m = fmaxf(m, __shfl_down(m, o, 64));
    if (lane == 0) sred[wave] = m;
    __syncthreads();
    float bm = sred[0];
#pragma unroll
    for (int i = 1; i < 16; ++i) bm = fmaxf(bm, sred[i]);
    __syncthreads();

    float s = 0.f;
    for (int i = tid; i < VOUTN / 4; i += 1024) {
        float4 v = r4[i];
        s += __expf(v.x - bm) + __expf(v.y - bm) + __expf(v.z - bm) + __expf(v.w - bm);
    }
    for (int o = 32; o; o >>= 1) s += __shfl_down(s, o, 64);
    if (lane == 0) sred[wave] = s;
    __syncthreads();
    float S = 0.f;
#pragma unroll
    for (int i = 0; i < 16; ++i) S += sred[i];
    float lse = bm + __logf(S);

    for (int i = tid; i < VOUTN / 4; i += 1024) {
        float4 v = r4[i];
        v.x -= lse; v.y -= lse; v.z -= lse; v.w -= lse;
        r4[i] = v;
    }
}

extern "C" void kernel_launch(void* const* d_in, const int* in_sizes, int n_in,
                              void* d_out, int out_size, void* d_ws, size_t ws_size,
                              hipStream_t stream) {
    const int*   src     = (const int*)d_in[0];
    const int*   trg     = (const int*)d_in[1];
    const int*   start   = (const int*)d_in[2];
    const float* enc_emb = (const float*)d_in[3];
    const float* enc_Wih = (const float*)d_in[4];
    const float* enc_Whh = (const float*)d_in[5];
    const float* enc_bih = (const float*)d_in[6];
    const float* enc_bhh = (const float*)d_in[7];
    const float* dec_emb = (const float*)d_in[8];
    const float* dec_Wih = (const float*)d_in[9];
    const float* dec_Whh = (const float*)d_in[10];
    const float* dec_bih = (const float*)d_in[11];
    const float* dec_bhh = (const float*)d_in[12];
    const float* lin_W   = (const float*)d_in[13];
    const float* lin_b   = (const float*)d_in[14];
    float* out = (float*)d_out;

    char* ws = (char*)d_ws;
    float*  encXW = (float*)(ws);                   // 256*4096 f32 = 4 MiB
    float*  decXW = (float*)(ws + 4194304);         // 4 MiB
    bf16_t* Hs    = (bf16_t*)(ws + 8388608);        // 256*1024 bf16 = 512 KiB
    u64*    hseq  = (u64*)(ws + 9437184);           // [512][1024] u64 = 4 MiB

    // input GEMMs (enc+dec) + hseq zeroing; 4 dispatches total
    xw_all<<<512, 64, 0, stream>>>(src, trg, start,
                                   enc_emb, enc_Wih, enc_bih, enc_bhh,
                                   dec_emb, dec_Wih, dec_bih, dec_bhh,
                                   encXW, decXW, hseq);

    // persistent recurrence: 128 co-resident WGs, 512 steps, dataflow sync
    lstm_seq<<<NWGC, 256, 0, stream>>>(encXW, decXW, enc_Whh, dec_Whh, hseq, Hs);

    // output projection + log_softmax
    out_gemm<<<500, 256, 0, stream>>>(Hs, lin_W, lin_b, out);
    log_softmax_k<<<256, 1024, 0, stream>>>(out);
}